// Round 6
// baseline (207.006 us; speedup 1.0000x reference)
//
#include <hip/hip_runtime.h>

// out[b] = sum_h [ dot(x1_bh,W1_h) + b1_h + dot(x2_bh,W2_h)
//                  + sum_o x2_bh[o] * dot(W3_h[o,:], x1_bh) ]
// B=16384, HEAD=8, DIM=128.
//
// R6 (from R5): amortize staging + kill the epilogue tail.
//  - grid (64,8): 512 blocks, head per block, 256 samples/block.
//    Outer mt-loop (2 sample-tiles of 16 per wave) around the kk-loop:
//    one 64 KB W3 staging serves 2x the MFMA work. Registers stay at R5
//    level (acc[8]=32 AGPR, ~70 VGPR) -> 2 blocks/CU at launch_bounds(512,4).
//  - Epilogue is barrier-free: t1 folded into the contrib owner lane via
//    __shfl_xor(16/32) + per-lane __shfl; 4 lanes/wave store one float4 of
//    psum directly. Only one __syncthreads in the kernel (after staging),
//    so waves drift and MFMA/VMEM overlap across waves hides gather latency.
//  - Numerics unchanged: split-bf16 3-pass (hi*hi+lo*hi+hi*lo), W3 pre-split
//    and fragment-ordered by prep kernel.
// Fragment layouts (verified m89/m91): A: m=lane&15, k=(lane>>4)*8+j;
//   B: n=lane&15, same k; C/D: col=lane&15, row=(lane>>4)*4+reg.
// ws: [0,256K) whi | [256K,512K) wlo | [512K,1M) psum float[8][16384]

#define NB 16384
#define NHEAD 8
#define NDIM 128

typedef __attribute__((ext_vector_type(8))) short bf16x8;
typedef __attribute__((ext_vector_type(4))) float f32x4;

// ---- prep: split W3 into bf16 hi/lo in MFMA B-fragment order ----
// t = ((h*4+kk)*8+nt)*64+lane ; writes whi[t*8..t*8+8)
__global__ __launch_bounds__(256) void prep_w3(
    const float* __restrict__ W3, short* __restrict__ whi,
    short* __restrict__ wlo)
{
    const int t    = blockIdx.x * 256 + threadIdx.x;   // 16384 threads
    const int lane = t & 63;
    const int nt   = (t >> 6) & 7;
    const int kk   = (t >> 9) & 3;
    const int h    = t >> 11;
    const int lm   = lane & 15;
    const int lg   = lane >> 4;

    const float* src = W3 + ((size_t)(h * NDIM + nt * 16 + lm)) * NDIM
                          + kk * 32 + lg * 8;
    const float4 a = *reinterpret_cast<const float4*>(src);
    const float4 b = *reinterpret_cast<const float4*>(src + 4);
    float xf[8] = {a.x, a.y, a.z, a.w, b.x, b.y, b.z, b.w};
    bf16x8 hi, lo;
#pragma unroll
    for (int j = 0; j < 8; ++j) {
        const unsigned u = __float_as_uint(xf[j]);
        hi[j] = (short)(u >> 16);
        const float hf = __uint_as_float(u & 0xffff0000u);
        lo[j] = (short)(__float_as_uint(xf[j] - hf) >> 16);
    }
    reinterpret_cast<bf16x8*>(whi)[t] = hi;
    reinterpret_cast<bf16x8*>(wlo)[t] = lo;
}

// ---- main: head per block, 8 waves, 2 m-tiles/wave = 256 samples/block ----
__global__ __launch_bounds__(512, 4) void bilinear_mfma(
    const float* __restrict__ x1, const float* __restrict__ x2,
    const float* __restrict__ W1, const float* __restrict__ W2,
    const short* __restrict__ whi, const short* __restrict__ wlo,
    float* __restrict__ psum)
{
    const int tid = threadIdx.x;
    const int w   = tid >> 6;
    const int l   = tid & 63;
    const int lm  = l & 15;
    const int lg  = l >> 4;
    const int h   = blockIdx.y;
    const int b0  = blockIdx.x * 256;
    const int bwb = b0 + w * 32;           // wave's 32 samples (2 tiles)

    __shared__ short lhi[4][8][512];       // 32 KB, fragment order
    __shared__ short llo[4][8][512];       // 32 KB

    // stage this head's pre-split W3 (64 KB) into LDS, linear copy
    {
        const float4* shi = reinterpret_cast<const float4*>(whi + (size_t)h * 16384);
        const float4* slo = reinterpret_cast<const float4*>(wlo + (size_t)h * 16384);
        float4* dhi = reinterpret_cast<float4*>(&lhi[0][0][0]);
        float4* dlo = reinterpret_cast<float4*>(&llo[0][0][0]);
#pragma unroll
        for (int i = 0; i < 4; ++i) {      // 2048 float4 per buffer
            dhi[i * 512 + tid] = shi[i * 512 + tid];
            dlo[i * 512 + tid] = slo[i * 512 + tid];
        }
    }
    __syncthreads();   // the only barrier; waves drift freely afterwards

    float w2v[8];
#pragma unroll
    for (int nt = 0; nt < 8; ++nt) w2v[nt] = W2[h * NDIM + nt * 16 + lm];
    const float* __restrict__ w1base = W1 + h * NDIM;

    for (int mt = 0; mt < 2; ++mt) {
        const int bw = bwb + mt * 16;

        f32x4 acc[8];
#pragma unroll
        for (int nt = 0; nt < 8; ++nt) acc[nt] = (f32x4)0.f;
        float t1 = 0.f;

#pragma unroll
        for (int kk = 0; kk < 4; ++kk) {
            const int k0 = kk * 32 + lg * 8;

            // A-fragment: split x1 in-register; t1 from exact fp32 values
            bf16x8 ahi, alo;
            {
                const float* xp = x1 + (size_t)(bw + lm) * (NHEAD * NDIM)
                                   + h * NDIM + k0;
                const float4 a  = *reinterpret_cast<const float4*>(xp);
                const float4 b  = *reinterpret_cast<const float4*>(xp + 4);
                const float4 wa = *reinterpret_cast<const float4*>(w1base + k0);
                const float4 wb = *reinterpret_cast<const float4*>(w1base + k0 + 4);
                float xf[8]  = {a.x, a.y, a.z, a.w, b.x, b.y, b.z, b.w};
                float w1f[8] = {wa.x, wa.y, wa.z, wa.w, wb.x, wb.y, wb.z, wb.w};
#pragma unroll
                for (int j = 0; j < 8; ++j) {
                    const unsigned u = __float_as_uint(xf[j]);
                    ahi[j] = (short)(u >> 16);
                    const float hf = __uint_as_float(u & 0xffff0000u);
                    alo[j] = (short)(__float_as_uint(xf[j] - hf) >> 16);
                    t1 += xf[j] * w1f[j];
                }
            }

            // B-fragments from LDS (conflict-free linear ds_read_b128)
#pragma unroll
            for (int nt = 0; nt < 8; ++nt) {
                const bf16x8 bhi = *reinterpret_cast<const bf16x8*>(&lhi[kk][nt][l * 8]);
                const bf16x8 blo = *reinterpret_cast<const bf16x8*>(&llo[kk][nt][l * 8]);
                acc[nt] = __builtin_amdgcn_mfma_f32_16x16x32_bf16(ahi, bhi, acc[nt], 0, 0, 0);
                acc[nt] = __builtin_amdgcn_mfma_f32_16x16x32_bf16(alo, bhi, acc[nt], 0, 0, 0);
                acc[nt] = __builtin_amdgcn_mfma_f32_16x16x32_bf16(ahi, blo, acc[nt], 0, 0, 0);
            }
        }

        // ---- barrier-free epilogue: sum_o (P+W2[o])*x2[b,o], fold t1 ----
        float cr[4];
#pragma unroll
        for (int r = 0; r < 4; ++r) {
            const float* x2p = x2 + (size_t)(bw + lg * 4 + r) * (NHEAD * NDIM)
                                + h * NDIM + lm;
            float s = 0.f;
#pragma unroll
            for (int nt = 0; nt < 8; ++nt)
                s += (acc[nt][r] + w2v[nt]) * x2p[nt * 16];
            cr[r] = s;
        }
#pragma unroll
        for (int m = 1; m < 16; m <<= 1)
#pragma unroll
            for (int r = 0; r < 4; ++r) cr[r] += __shfl_xor(cr[r], m, 64);

        // t1: sum over lg groups -> every lane holds T(bw + (l&15))
        float tf = t1;
        tf += __shfl_xor(tf, 16, 64);
        tf += __shfl_xor(tf, 32, 64);
#pragma unroll
        for (int r = 0; r < 4; ++r) cr[r] += __shfl(tf, lg * 4 + r, 64);

        if (lm == 0) {
            float4 st;
            st.x = cr[0]; st.y = cr[1]; st.z = cr[2]; st.w = cr[3];
            *reinterpret_cast<float4*>(&psum[(size_t)h * NB + bw + lg * 4]) = st;
        }
    }
}

__global__ __launch_bounds__(256) void bilinear_reduce(
    const float* __restrict__ psum, const float* __restrict__ b1,
    float* __restrict__ out)
{
    const int i = blockIdx.x * 256 + threadIdx.x;
    float bs = 0.f;
#pragma unroll
    for (int hh = 0; hh < NHEAD; ++hh) bs += b1[hh];
    float s = bs;
#pragma unroll
    for (int hh = 0; hh < NHEAD; ++hh) s += psum[(size_t)hh * NB + i];
    out[i] = s;
}

extern "C" void kernel_launch(void* const* d_in, const int* in_sizes, int n_in,
                              void* d_out, int out_size, void* d_ws, size_t ws_size,
                              hipStream_t stream) {
    const float* x1 = (const float*)d_in[0];
    const float* x2 = (const float*)d_in[1];
    const float* W1 = (const float*)d_in[2];
    const float* b1 = (const float*)d_in[3];
    const float* W2 = (const float*)d_in[4];
    const float* W3 = (const float*)d_in[5];
    float* out = (float*)d_out;

    short* whi = (short*)d_ws;                          // 256 KB
    short* wlo = whi + (size_t)NHEAD * NDIM * NDIM;     // 256 KB
    float* psum = (float*)((char*)d_ws + 512 * 1024);   // 512 KB

    prep_w3<<<dim3(64), dim3(256), 0, stream>>>(W3, whi, wlo);
    bilinear_mfma<<<dim3(NB / 256, NHEAD), dim3(512), 0, stream>>>(
        x1, x2, W1, W2, whi, wlo, psum);
    bilinear_reduce<<<dim3(NB / 256), dim3(256), 0, stream>>>(psum, b1, out);
}

// Round 7
// 36.286 us; speedup vs baseline: 5.7049x; 5.7049x over previous
//
#include <hip/hip_runtime.h>

// out[b] = sum_h [ dot(x1_bh,W1_h) + b1_h + dot(x2_bh,W2_h)
//                  + sum_o x2_bh[o] * dot(W3_h[o,:], x1_bh) ]
// B=16384, HEAD=8, DIM=128.
//
// R7 (from R5-proven core; R6's mt-unroll spill reverted):
//  - Block = 256 thr = 4 waves, head per block, 64 samples. Grid (256, 8).
//  - LDS cut 64->16 KB: stage ONE kk-slab (8 nt x 512 shorts, hi+lo) per
//    phase, 4 phases with double barriers; acc[8] persists across phases.
//    Occupancy now reg-limited (~100 regs -> target 5 waves/EU) instead of
//    LDS-limited (R5: 64 KB -> 2 blocks/CU -> 2.9 waves/SIMD).
//  - x1 A-fragment software-pipelined one kk ahead (loads in flight across
//    the phase barriers, split+MFMA never waits on global latency).
//  - Barrier-free epilogue (verified in R6): shfl-reduce + t1 fold via
//    __shfl, 4 lanes store one float4 of psum.
//  - Numerics unchanged: split-bf16 3-pass (hi*hi+lo*hi+hi*lo), W3 pre-split
//    fragment-ordered by prep kernel.
// Fragment layouts (verified m89/m91): A: m=lane&15, k=(lane>>4)*8+j;
//   B: n=lane&15, same k; C/D: col=lane&15, row=(lane>>4)*4+reg.
// ws: [0,256K) whi | [256K,512K) wlo | [512K,1M) psum float[8][16384]

#define NB 16384
#define NHEAD 8
#define NDIM 128

typedef __attribute__((ext_vector_type(8))) short bf16x8;
typedef __attribute__((ext_vector_type(4))) float f32x4;

// ---- prep: split W3 into bf16 hi/lo in MFMA B-fragment order ----
// t = ((h*4+kk)*8+nt)*64+lane ; writes whi[t*8..t*8+8)
__global__ __launch_bounds__(256) void prep_w3(
    const float* __restrict__ W3, short* __restrict__ whi,
    short* __restrict__ wlo)
{
    const int t    = blockIdx.x * 256 + threadIdx.x;   // 16384 threads
    const int lane = t & 63;
    const int nt   = (t >> 6) & 7;
    const int kk   = (t >> 9) & 3;
    const int h    = t >> 11;
    const int lm   = lane & 15;
    const int lg   = lane >> 4;

    const float* src = W3 + ((size_t)(h * NDIM + nt * 16 + lm)) * NDIM
                          + kk * 32 + lg * 8;
    const float4 a = *reinterpret_cast<const float4*>(src);
    const float4 b = *reinterpret_cast<const float4*>(src + 4);
    float xf[8] = {a.x, a.y, a.z, a.w, b.x, b.y, b.z, b.w};
    bf16x8 hi, lo;
#pragma unroll
    for (int j = 0; j < 8; ++j) {
        const unsigned u = __float_as_uint(xf[j]);
        hi[j] = (short)(u >> 16);
        const float hf = __uint_as_float(u & 0xffff0000u);
        lo[j] = (short)(__float_as_uint(xf[j] - hf) >> 16);
    }
    reinterpret_cast<bf16x8*>(whi)[t] = hi;
    reinterpret_cast<bf16x8*>(wlo)[t] = lo;
}

// ---- main: head per block, 4 waves x 16 samples = 64 samples/block ----
__global__ __launch_bounds__(256, 4) void bilinear_mfma(
    const float* __restrict__ x1, const float* __restrict__ x2,
    const float* __restrict__ W1, const float* __restrict__ W2,
    const short* __restrict__ whi, const short* __restrict__ wlo,
    float* __restrict__ psum)
{
    const int tid = threadIdx.x;
    const int w   = tid >> 6;
    const int l   = tid & 63;
    const int lm  = l & 15;
    const int lg  = l >> 4;
    const int h   = blockIdx.y;
    const int b0  = blockIdx.x * 64;
    const int bw  = b0 + w * 16;           // wave's 16 samples

    __shared__ short lhi[8][512];          // 8 KB: one kk-slab, frag order
    __shared__ short llo[8][512];          // 8 KB

    const float* __restrict__ w1base = W1 + h * NDIM;
    const float* __restrict__ x1base = x1 + (size_t)(bw + lm) * (NHEAD * NDIM)
                                          + h * NDIM + lg * 8;
    // per-kk staging sources (8 KB slabs = 512 float4), fragment-ordered
    const float4* __restrict__ shi = reinterpret_cast<const float4*>(
        whi + (size_t)h * 16384);
    const float4* __restrict__ slo = reinterpret_cast<const float4*>(
        wlo + (size_t)h * 16384);

    f32x4 acc[8];
#pragma unroll
    for (int nt = 0; nt < 8; ++nt) acc[nt] = (f32x4)0.f;
    float t1 = 0.f;

    // prefetch kk=0 A-fragment source
    float4 pa = *reinterpret_cast<const float4*>(x1base);
    float4 pb = *reinterpret_cast<const float4*>(x1base + 4);

#pragma unroll
    for (int kk = 0; kk < 4; ++kk) {
        // ---- stage kk-slab: 512 float4 per buffer, 2 per thread ----
        {
            const float4 h0 = shi[kk * 512 + tid];
            const float4 h1 = shi[kk * 512 + tid + 256];
            const float4 l0 = slo[kk * 512 + tid];
            const float4 l1 = slo[kk * 512 + tid + 256];
            float4* dhi = reinterpret_cast<float4*>(&lhi[0][0]);
            float4* dlo = reinterpret_cast<float4*>(&llo[0][0]);
            dhi[tid]       = h0;
            dhi[tid + 256] = h1;
            dlo[tid]       = l0;
            dlo[tid + 256] = l1;
        }
        __syncthreads();   // slab visible

        // consume prefetched x1, issue next kk's loads (fly over barriers)
        const float4 ca = pa, cb = pb;
        if (kk < 3) {
            pa = *reinterpret_cast<const float4*>(x1base + (kk + 1) * 32);
            pb = *reinterpret_cast<const float4*>(x1base + (kk + 1) * 32 + 4);
        }

        // A-fragment split + t1 from exact fp32 values
        bf16x8 ahi, alo;
        {
            const int k0 = kk * 32 + lg * 8;
            const float4 wa = *reinterpret_cast<const float4*>(w1base + k0);
            const float4 wb = *reinterpret_cast<const float4*>(w1base + k0 + 4);
            float xf[8]  = {ca.x, ca.y, ca.z, ca.w, cb.x, cb.y, cb.z, cb.w};
            float w1f[8] = {wa.x, wa.y, wa.z, wa.w, wb.x, wb.y, wb.z, wb.w};
#pragma unroll
            for (int j = 0; j < 8; ++j) {
                const unsigned u = __float_as_uint(xf[j]);
                ahi[j] = (short)(u >> 16);
                const float hf = __uint_as_float(u & 0xffff0000u);
                alo[j] = (short)(__float_as_uint(xf[j] - hf) >> 16);
                t1 += xf[j] * w1f[j];
            }
        }

        // B-fragments from LDS (linear ds_read_b128, conflict-free)
#pragma unroll
        for (int nt = 0; nt < 8; ++nt) {
            const bf16x8 bhi = *reinterpret_cast<const bf16x8*>(&lhi[nt][l * 8]);
            const bf16x8 blo = *reinterpret_cast<const bf16x8*>(&llo[nt][l * 8]);
            acc[nt] = __builtin_amdgcn_mfma_f32_16x16x32_bf16(ahi, bhi, acc[nt], 0, 0, 0);
            acc[nt] = __builtin_amdgcn_mfma_f32_16x16x32_bf16(alo, bhi, acc[nt], 0, 0, 0);
            acc[nt] = __builtin_amdgcn_mfma_f32_16x16x32_bf16(ahi, blo, acc[nt], 0, 0, 0);
        }
        __syncthreads();   // all waves done reading before next stage
    }

    // ---- barrier-free epilogue: sum_o (P+W2[o])*x2[b,o], fold t1 ----
    float w2v[8];
#pragma unroll
    for (int nt = 0; nt < 8; ++nt) w2v[nt] = W2[h * NDIM + nt * 16 + lm];

    float cr[4];
#pragma unroll
    for (int r = 0; r < 4; ++r) {
        const float* x2p = x2 + (size_t)(bw + lg * 4 + r) * (NHEAD * NDIM)
                            + h * NDIM + lm;
        float s = 0.f;
#pragma unroll
        for (int nt = 0; nt < 8; ++nt)
            s += (acc[nt][r] + w2v[nt]) * x2p[nt * 16];
        cr[r] = s;
    }
#pragma unroll
    for (int m = 1; m < 16; m <<= 1)
#pragma unroll
        for (int r = 0; r < 4; ++r) cr[r] += __shfl_xor(cr[r], m, 64);

    // t1: sum over lg groups -> every lane holds T(bw + (l&15))
    float tf = t1;
    tf += __shfl_xor(tf, 16, 64);
    tf += __shfl_xor(tf, 32, 64);
#pragma unroll
    for (int r = 0; r < 4; ++r) cr[r] += __shfl(tf, lg * 4 + r, 64);

    if (lm == 0) {
        float4 st;
        st.x = cr[0]; st.y = cr[1]; st.z = cr[2]; st.w = cr[3];
        *reinterpret_cast<float4*>(&psum[(size_t)h * NB + bw + lg * 4]) = st;
    }
}

__global__ __launch_bounds__(256) void bilinear_reduce(
    const float* __restrict__ psum, const float* __restrict__ b1,
    float* __restrict__ out)
{
    const int i = blockIdx.x * 256 + threadIdx.x;
    float bs = 0.f;
#pragma unroll
    for (int hh = 0; hh < NHEAD; ++hh) bs += b1[hh];
    float s = bs;
#pragma unroll
    for (int hh = 0; hh < NHEAD; ++hh) s += psum[(size_t)hh * NB + i];
    out[i] = s;
}

extern "C" void kernel_launch(void* const* d_in, const int* in_sizes, int n_in,
                              void* d_out, int out_size, void* d_ws, size_t ws_size,
                              hipStream_t stream) {
    const float* x1 = (const float*)d_in[0];
    const float* x2 = (const float*)d_in[1];
    const float* W1 = (const float*)d_in[2];
    const float* b1 = (const float*)d_in[3];
    const float* W2 = (const float*)d_in[4];
    const float* W3 = (const float*)d_in[5];
    float* out = (float*)d_out;

    short* whi = (short*)d_ws;                          // 256 KB
    short* wlo = whi + (size_t)NHEAD * NDIM * NDIM;     // 256 KB
    float* psum = (float*)((char*)d_ws + 512 * 1024);   // 512 KB

    prep_w3<<<dim3(64), dim3(256), 0, stream>>>(W3, whi, wlo);
    bilinear_mfma<<<dim3(NB / 64, NHEAD), dim3(256), 0, stream>>>(
        x1, x2, W1, W2, whi, wlo, psum);
    bilinear_reduce<<<dim3(NB / 256), dim3(256), 0, stream>>>(psum, b1, out);
}

// Round 8
// 35.850 us; speedup vs baseline: 5.7742x; 1.0122x over previous
//
#include <hip/hip_runtime.h>

// out[b] = sum_h [ dot(x1_bh,W1_h) + b1_h + dot(x2_bh,W2_h)
//                  + sum_o x2_bh[o] * dot(W3_h[o,:], x1_bh) ]
// B=16384, HEAD=8, DIM=128.
//
// R8 (from R7): break the serial stage->barrier->compute chain.
//  - LDS double-buffer (2 x 16 KB slabs): at the TOP of phase kk, issue
//    global loads for slab kk+1 into regs; compute kk from buf[kk&1];
//    ds_write buf[(kk+1)&1]; ONE barrier per phase. Global latency hides
//    under the phase's MFMA+split compute. (T3 minimum pipeline, reg-staged.)
//  - 1D grid, head = bid & 7: round-robin XCD dispatch pins each head to one
//    XCD -> its 128 KB pre-split W3 stays L2-resident.
//  - Everything else identical to R7 (proven): split-bf16 3-pass numerics,
//    barrier-free shuffle epilogue, psum + reduce kernel.
// Fragment layouts (verified m89/m91): A: m=lane&15, k=(lane>>4)*8+j;
//   B: n=lane&15, same k; C/D: col=lane&15, row=(lane>>4)*4+reg.
// ws: [0,256K) whi | [256K,512K) wlo | [512K,1M) psum float[8][16384]

#define NB 16384
#define NHEAD 8
#define NDIM 128

typedef __attribute__((ext_vector_type(8))) short bf16x8;
typedef __attribute__((ext_vector_type(4))) float f32x4;

// ---- prep: split W3 into bf16 hi/lo in MFMA B-fragment order ----
// t = ((h*4+kk)*8+nt)*64+lane ; writes whi[t*8..t*8+8)
__global__ __launch_bounds__(256) void prep_w3(
    const float* __restrict__ W3, short* __restrict__ whi,
    short* __restrict__ wlo)
{
    const int t    = blockIdx.x * 256 + threadIdx.x;   // 16384 threads
    const int lane = t & 63;
    const int nt   = (t >> 6) & 7;
    const int kk   = (t >> 9) & 3;
    const int h    = t >> 11;
    const int lm   = lane & 15;
    const int lg   = lane >> 4;

    const float* src = W3 + ((size_t)(h * NDIM + nt * 16 + lm)) * NDIM
                          + kk * 32 + lg * 8;
    const float4 a = *reinterpret_cast<const float4*>(src);
    const float4 b = *reinterpret_cast<const float4*>(src + 4);
    float xf[8] = {a.x, a.y, a.z, a.w, b.x, b.y, b.z, b.w};
    bf16x8 hi, lo;
#pragma unroll
    for (int j = 0; j < 8; ++j) {
        const unsigned u = __float_as_uint(xf[j]);
        hi[j] = (short)(u >> 16);
        const float hf = __uint_as_float(u & 0xffff0000u);
        lo[j] = (short)(__float_as_uint(xf[j] - hf) >> 16);
    }
    reinterpret_cast<bf16x8*>(whi)[t] = hi;
    reinterpret_cast<bf16x8*>(wlo)[t] = lo;
}

// ---- main: head = bid&7, 4 waves x 16 samples = 64 samples/block ----
__global__ __launch_bounds__(256, 4) void bilinear_mfma(
    const float* __restrict__ x1, const float* __restrict__ x2,
    const float* __restrict__ W1, const float* __restrict__ W2,
    const short* __restrict__ whi, const short* __restrict__ wlo,
    float* __restrict__ psum)
{
    const int tid = threadIdx.x;
    const int w   = tid >> 6;
    const int l   = tid & 63;
    const int lm  = l & 15;
    const int lg  = l >> 4;
    const int bid = blockIdx.x;
    const int h   = bid & 7;               // head pinned per-XCD (round-robin)
    const int b0  = (bid >> 3) * 64;
    const int bw  = b0 + w * 16;           // wave's 16 samples

    __shared__ short lhi[2][4096];         // 2 x 8 KB slabs, frag order
    __shared__ short llo[2][4096];         // 2 x 8 KB

    const float4* __restrict__ shi = reinterpret_cast<const float4*>(
        whi + (size_t)h * 16384);
    const float4* __restrict__ slo = reinterpret_cast<const float4*>(
        wlo + (size_t)h * 16384);

    const float* __restrict__ w1base = W1 + h * NDIM;
    const float* __restrict__ x1base = x1 + (size_t)(bw + lm) * (NHEAD * NDIM)
                                          + h * NDIM + lg * 8;

    f32x4 acc[8];
#pragma unroll
    for (int nt = 0; nt < 8; ++nt) acc[nt] = (f32x4)0.f;
    float t1 = 0.f;

    // prologue: stage slab 0 into buf 0; prefetch kk=0 x1 fragment
    {
        const float4 a0 = shi[tid];
        const float4 a1 = shi[tid + 256];
        const float4 c0 = slo[tid];
        const float4 c1 = slo[tid + 256];
        reinterpret_cast<float4*>(&lhi[0][0])[0 + tid]   = a0;
        reinterpret_cast<float4*>(&lhi[0][0])[256 + tid] = a1;
        reinterpret_cast<float4*>(&llo[0][0])[0 + tid]   = c0;
        reinterpret_cast<float4*>(&llo[0][0])[256 + tid] = c1;
    }
    float4 pa = *reinterpret_cast<const float4*>(x1base);
    float4 pb = *reinterpret_cast<const float4*>(x1base + 4);
    __syncthreads();

#pragma unroll
    for (int kk = 0; kk < 4; ++kk) {
        const int cur = kk & 1;
        const int nxt = (kk + 1) & 1;

        // issue NEXT slab's global loads first (latency flies over compute)
        float4 nh0, nh1, nl0, nl1;
        if (kk < 3) {
            nh0 = shi[(kk + 1) * 512 + tid];
            nh1 = shi[(kk + 1) * 512 + tid + 256];
            nl0 = slo[(kk + 1) * 512 + tid];
            nl1 = slo[(kk + 1) * 512 + tid + 256];
        }
        const float4 ca = pa, cb = pb;
        if (kk < 3) {
            pa = *reinterpret_cast<const float4*>(x1base + (kk + 1) * 32);
            pb = *reinterpret_cast<const float4*>(x1base + (kk + 1) * 32 + 4);
        }

        // A-fragment split + t1 from exact fp32 values
        bf16x8 ahi, alo;
        {
            const int k0 = kk * 32 + lg * 8;
            const float4 wa = *reinterpret_cast<const float4*>(w1base + k0);
            const float4 wb = *reinterpret_cast<const float4*>(w1base + k0 + 4);
            float xf[8]  = {ca.x, ca.y, ca.z, ca.w, cb.x, cb.y, cb.z, cb.w};
            float w1f[8] = {wa.x, wa.y, wa.z, wa.w, wb.x, wb.y, wb.z, wb.w};
#pragma unroll
            for (int j = 0; j < 8; ++j) {
                const unsigned u = __float_as_uint(xf[j]);
                ahi[j] = (short)(u >> 16);
                const float hf = __uint_as_float(u & 0xffff0000u);
                alo[j] = (short)(__float_as_uint(xf[j] - hf) >> 16);
                t1 += xf[j] * w1f[j];
            }
        }

        // B-fragments from LDS buf[cur] (linear ds_read_b128, conflict-free)
#pragma unroll
        for (int nt = 0; nt < 8; ++nt) {
            const bf16x8 bhi = *reinterpret_cast<const bf16x8*>(
                &lhi[cur][nt * 512 + l * 8]);
            const bf16x8 blo = *reinterpret_cast<const bf16x8*>(
                &llo[cur][nt * 512 + l * 8]);
            acc[nt] = __builtin_amdgcn_mfma_f32_16x16x32_bf16(ahi, bhi, acc[nt], 0, 0, 0);
            acc[nt] = __builtin_amdgcn_mfma_f32_16x16x32_bf16(alo, bhi, acc[nt], 0, 0, 0);
            acc[nt] = __builtin_amdgcn_mfma_f32_16x16x32_bf16(ahi, blo, acc[nt], 0, 0, 0);
        }

        // write next slab into the other buffer (readers passed last barrier)
        if (kk < 3) {
            reinterpret_cast<float4*>(&lhi[nxt][0])[0 + tid]   = nh0;
            reinterpret_cast<float4*>(&lhi[nxt][0])[256 + tid] = nh1;
            reinterpret_cast<float4*>(&llo[nxt][0])[0 + tid]   = nl0;
            reinterpret_cast<float4*>(&llo[nxt][0])[256 + tid] = nl1;
        }
        __syncthreads();
    }

    // ---- barrier-free epilogue: sum_o (P+W2[o])*x2[b,o], fold t1 ----
    float w2v[8];
#pragma unroll
    for (int nt = 0; nt < 8; ++nt) w2v[nt] = W2[h * NDIM + nt * 16 + lm];

    float cr[4];
#pragma unroll
    for (int r = 0; r < 4; ++r) {
        const float* x2p = x2 + (size_t)(bw + lg * 4 + r) * (NHEAD * NDIM)
                            + h * NDIM + lm;
        float s = 0.f;
#pragma unroll
        for (int nt = 0; nt < 8; ++nt)
            s += (acc[nt][r] + w2v[nt]) * x2p[nt * 16];
        cr[r] = s;
    }
#pragma unroll
    for (int m = 1; m < 16; m <<= 1)
#pragma unroll
        for (int r = 0; r < 4; ++r) cr[r] += __shfl_xor(cr[r], m, 64);

    // t1: sum over lg groups -> every lane holds T(bw + (l&15))
    float tf = t1;
    tf += __shfl_xor(tf, 16, 64);
    tf += __shfl_xor(tf, 32, 64);
#pragma unroll
    for (int r = 0; r < 4; ++r) cr[r] += __shfl(tf, lg * 4 + r, 64);

    if (lm == 0) {
        float4 st;
        st.x = cr[0]; st.y = cr[1]; st.z = cr[2]; st.w = cr[3];
        *reinterpret_cast<float4*>(&psum[(size_t)h * NB + bw + lg * 4]) = st;
    }
}

__global__ __launch_bounds__(256) void bilinear_reduce(
    const float* __restrict__ psum, const float* __restrict__ b1,
    float* __restrict__ out)
{
    const int i = blockIdx.x * 256 + threadIdx.x;
    float bs = 0.f;
#pragma unroll
    for (int hh = 0; hh < NHEAD; ++hh) bs += b1[hh];
    float s = bs;
#pragma unroll
    for (int hh = 0; hh < NHEAD; ++hh) s += psum[(size_t)hh * NB + i];
    out[i] = s;
}

extern "C" void kernel_launch(void* const* d_in, const int* in_sizes, int n_in,
                              void* d_out, int out_size, void* d_ws, size_t ws_size,
                              hipStream_t stream) {
    const float* x1 = (const float*)d_in[0];
    const float* x2 = (const float*)d_in[1];
    const float* W1 = (const float*)d_in[2];
    const float* b1 = (const float*)d_in[3];
    const float* W2 = (const float*)d_in[4];
    const float* W3 = (const float*)d_in[5];
    float* out = (float*)d_out;

    short* whi = (short*)d_ws;                          // 256 KB
    short* wlo = whi + (size_t)NHEAD * NDIM * NDIM;     // 256 KB
    float* psum = (float*)((char*)d_ws + 512 * 1024);   // 512 KB

    prep_w3<<<dim3(64), dim3(256), 0, stream>>>(W3, whi, wlo);
    bilinear_mfma<<<dim3(NB / 64 * NHEAD), dim3(256), 0, stream>>>(
        x1, x2, W1, W2, whi, wlo, psum);
    bilinear_reduce<<<dim3(NB / 256), dim3(256), 0, stream>>>(psum, b1, out);
}